// Round 15
// baseline (345.047 us; speedup 1.0000x reference)
//
#include <hip/hip_runtime.h>

typedef unsigned short u16;
typedef unsigned int u32;
using s16x8 = __attribute__((ext_vector_type(8))) short;
using f32x4 = __attribute__((ext_vector_type(4))) float;
using u16x4 = __attribute__((ext_vector_type(4))) u16;

#define DEV __device__ __forceinline__

DEV u16 f2bf(float f) {
    u32 u = __builtin_bit_cast(u32, f);
    u32 r = (u + 0x7FFFu + ((u >> 16) & 1u)) >> 16;
    return (u16)r;
}
DEV float bf2f(u16 h) { return __builtin_bit_cast(float, ((u32)h) << 16); }

DEV f32x4 mfma16(s16x8 a, s16x8 b, f32x4 c) {
    return __builtin_amdgcn_mfma_f32_16x16x32_bf16(a, b, c, 0, 0, 0);
}

#define GLOAD(g, l) __builtin_amdgcn_global_load_lds( \
    (const __attribute__((address_space(1))) unsigned int*)(g), \
    (__attribute__((address_space(3))) unsigned int*)(l), 16, 0, 0)

// ---------------------------------------------------------------- prep (+ starts scan in last block)
__global__ void k_prep(const float* W1, const float* W2, const float* Wl,
                       const float* Wc1, const float* Wc2, const float* Wc3,
                       const float* Wc4, const float* Wc5,
                       u16* WpT, u16* WlT, u16* WcT,
                       const int* sizes, int* starts) {
    int tid = threadIdx.x;
    if (blockIdx.x == 5760) {
        __shared__ int ps[256];
        int t4 = tid * 4;
        int v0 = sizes[t4], v1 = sizes[t4 + 1], v2 = sizes[t4 + 2], v3 = sizes[t4 + 3];
        int sum = v0 + v1 + v2 + v3;
        ps[tid] = sum;
        __syncthreads();
        for (int off = 1; off < 256; off <<= 1) {
            int add = (tid >= off) ? ps[tid - off] : 0;
            __syncthreads();
            ps[tid] += add;
            __syncthreads();
        }
        int base = tid ? ps[tid - 1] : 0;
        starts[t4] = base;
        starts[t4 + 1] = base + v0;
        starts[t4 + 2] = base + v0 + v1;
        starts[t4 + 3] = base + v0 + v1 + v2;
        return;
    }
    int idx = blockIdx.x * 256 + tid;
    if (idx < 512 * 320) {
        int n = idx / 320, k = idx - n * 320;
        float v = 0.f;
        if (k < 300) v = (n < 256) ? W1[k * 256 + n] : W2[k * 256 + (n - 256)];
        WpT[idx] = f2bf(v);
    } else if (idx < 512 * 320 + 256 * 1280) {
        int j2 = idx - 512 * 320;
        int m = j2 / 1280, j = j2 - m * 1280;
        WlT[j2] = f2bf(Wl[j * 256 + m]);
    } else {
        int j3 = idx - (512 * 320 + 256 * 1280);
        if (j3 < 983040) {
            int wsz; int off;
            if (j3 < 65536)       { wsz = 1; off = 0; }
            else if (j3 < 196608) { wsz = 2; off = 65536; }
            else if (j3 < 393216) { wsz = 3; off = 196608; }
            else if (j3 < 655360) { wsz = 4; off = 393216; }
            else                  { wsz = 5; off = 655360; }
            int loc = j3 - off;
            int o = loc / (256 * wsz);
            int kk = loc - o * (256 * wsz);
            int dw = kk >> 8, i = kk & 255;
            const float* W = (wsz == 1) ? Wc1 : (wsz == 2) ? Wc2 : (wsz == 3) ? Wc3
                             : (wsz == 4) ? Wc4 : Wc5;
            WcT[j3] = f2bf(W[(o * 256 + i) * wsz + dw]);
        }
    }
}

// ---------------------------------------------------------------- gather: xg[row][320] bf16 = emb[token(row)]
__launch_bounds__(512)
__global__ void k_gather(const int* data_as, const int* data_q, const float* emb,
                         u16* xg, int Ttot) {
    int j = blockIdx.x * 512 + threadIdx.x;
    int R = Ttot + 64;
    int row = j / 80;
    if (row >= R) return;
    int slot = j - row * 80;
    int tok = (row < Ttot) ? data_as[row] : data_q[row - Ttot];
    u16x4 h = {0, 0, 0, 0};
    if (slot < 75) {
        float4 f = *(const float4*)(emb + (long)tok * 300 + slot * 4);
        h[0] = f2bf(f.x); h[1] = f2bf(f.y); h[2] = f2bf(f.z); h[3] = f2bf(f.w);
    }
    *(u16x4*)(xg + (long)row * 320 + slot * 4) = h;
}

// ---------------------------------------------------------------- projection GEMM (GLOAD-staged from xg)
__launch_bounds__(512)
__global__ void k_pgemm(const u16* xg, const u16* WpT, const float* b1, const float* b2,
                        u16* ap, u16* qp, int Ttot) {
    __shared__ u16 X[64 * 320];   // row pitch 640B, granule-XOR-swizzled storage
    int tid = threadIdx.x;
    bool isq = (blockIdx.x == 1024);
    u16* out = isq ? qp : ap;
    long row0 = isq ? 0 : (long)blockIdx.x * 64;
    long grow0 = isq ? Ttot : row0;           // row base in xg
    int wv = tid >> 6, lane = tid & 63, l15 = lane & 15, lq = lane >> 4;
    {
#pragma unroll
        for (int i = 0; i < 5; ++i) {
            int G = wv * 320 + i * 64 + lane;   // flat granule
            int rr = G / 40;                    // tile row 0..63
            int g = G - rr * 40;                // physical granule in row
            int gs = g ^ (rr & 7);              // source (logical) granule
            const char* src = (const char*)(xg + (grow0 + rr) * 320) + gs * 16;
            GLOAD(src, (char*)X + wv * 5120 + i * 1024);
        }
    }
    __syncthreads();
    f32x4 acc[4][4] = {};
    for (int s = 0; s < 10; ++s) {
        s16x8 a[4], b[4];
#pragma unroll
        for (int c = 0; c < 4; ++c) {
            int mt = 2 * wv + (c & 1) + (c >> 1) * 16;
            int o = mt * 16 + l15;
            a[c] = *(const s16x8*)(WpT + o * 320 + s * 32 + lq * 8);
        }
#pragma unroll
        for (int nt = 0; nt < 4; ++nt) {
            int r = nt * 16 + l15;
            b[nt] = *(const s16x8*)((const char*)X + r * 640 +
                                    ((u32)(s * 64 + lq * 16) ^ ((u32)(r & 7) << 4)));
        }
#pragma unroll
        for (int c = 0; c < 4; ++c)
#pragma unroll
            for (int nt = 0; nt < 4; ++nt)
                acc[c][nt] = mfma16(a[c], b[nt], acc[c][nt]);
    }
    __syncthreads();
    u16* Y = X; // reuse as [64][264] (pitch 264 u16 -> bank spread)
#pragma unroll
    for (int c = 0; c < 2; ++c) {
        int o0 = (2 * wv + c) * 16 + lq * 4;
#pragma unroll
        for (int nt = 0; nt < 4; ++nt) {
            int t = nt * 16 + l15;
            u16x4 h4;
#pragma unroll
            for (int r = 0; r < 4; ++r) {
                float xs = acc[c][nt][r] + b1[o0 + r];
                float xt = acc[c + 2][nt][r] + b2[o0 + r];
                float v = (1.f / (1.f + __expf(-xs))) * tanhf(xt);
                h4[r] = f2bf(v);
            }
            *(u16x4*)((char*)Y + t * 528 + o0 * 2) = h4;
        }
    }
    __syncthreads();
    for (int j = tid; j < 2048; j += 512) {
        int t = j >> 5, c8 = (j & 31) * 8;
        *(s16x8*)(out + (row0 + t) * 256 + c8) =
            *(const s16x8*)((const char*)Y + t * 528 + c8 * 2);
    }
}

// ---------------------------------------------------------------- att + lean in-register softmax stats
__launch_bounds__(256)
__global__ void k_att(const u16* qp, const u16* ap, float* att,
                      float* partm, float* parts) {
    __shared__ u16 Q[64 * 256];
    __shared__ u16 A[64 * 256];
    __shared__ float Pm[8][64], Ps[8][64], Qm[64];
    int tid = threadIdx.x;
    long t0 = (long)blockIdx.x * 64;
    for (int j = tid; j < 2048; j += 256) {
        int r = j >> 5, c8 = (j & 31) * 8;
        u32 dst = (u32)(c8 * 2) ^ ((u32)(r & 7) << 4);
        *(s16x8*)((char*)Q + r * 512 + dst) = *(const s16x8*)(qp + r * 256 + c8);
        *(s16x8*)((char*)A + r * 512 + dst) = *(const s16x8*)(ap + (t0 + r) * 256 + c8);
    }
    __syncthreads();
    int wv = tid >> 6, lane = tid & 63, l15 = lane & 15, lq = lane >> 4;
    f32x4 acc[4] = {};
    for (int s = 0; s < 8; ++s) {
        int brow = wv * 16 + l15;
        s16x8 b = *(const s16x8*)((const char*)A + brow * 512 +
                                  ((u32)(s * 64 + lq * 16) ^ ((u32)(brow & 7) << 4)));
#pragma unroll
        for (int mt = 0; mt < 4; ++mt) {
            int arow = mt * 16 + l15;
            s16x8 a = *(const s16x8*)((const char*)Q + arow * 512 +
                                      ((u32)(s * 64 + lq * 16) ^ ((u32)(arow & 7) << 4)));
            acc[mt] = mfma16(a, b, acc[mt]);
        }
    }
#pragma unroll
    for (int mt = 0; mt < 4; ++mt) {
        long t = t0 + wv * 16 + l15;
        *(f32x4*)(att + t * 64 + mt * 16 + lq * 4) = acc[mt];
    }
    float mxv[16];
#pragma unroll
    for (int mt = 0; mt < 4; ++mt)
#pragma unroll
        for (int r = 0; r < 4; ++r) mxv[mt * 4 + r] = acc[mt][r];
#pragma unroll
    for (int off = 1; off <= 8; off <<= 1)
#pragma unroll
        for (int i = 0; i < 16; ++i)
            mxv[i] = fmaxf(mxv[i], __shfl_xor(mxv[i], off, 64));
    if (l15 == 0) {
#pragma unroll
        for (int mt = 0; mt < 4; ++mt)
#pragma unroll
            for (int r = 0; r < 4; ++r)
                Pm[wv][mt * 16 + lq * 4 + r] = mxv[mt * 4 + r];
    }
    __syncthreads();
    if (tid < 64) {
        float g = Pm[0][tid];
#pragma unroll
        for (int i = 1; i < 8; ++i) g = fmaxf(g, Pm[i][tid]);
        Qm[tid] = g;
    }
    __syncthreads();
    float sv[16];
#pragma unroll
    for (int mt = 0; mt < 4; ++mt)
#pragma unroll
        for (int r = 0; r < 4; ++r) {
            int q = mt * 16 + lq * 4 + r;
            sv[mt * 4 + r] = __expf(acc[mt][r] - Qm[q]);
        }
#pragma unroll
    for (int off = 1; off <= 8; off <<= 1)
#pragma unroll
        for (int i = 0; i < 16; ++i)
            sv[i] += __shfl_xor(sv[i], off, 64);
    if (l15 == 0) {
#pragma unroll
        for (int mt = 0; mt < 4; ++mt)
#pragma unroll
            for (int r = 0; r < 4; ++r)
                Ps[wv][mt * 16 + lq * 4 + r] = sv[mt * 4 + r];
    }
    __syncthreads();
    if (tid < 64) {
        float s = Ps[0][tid];
#pragma unroll
        for (int i = 1; i < 8; ++i) s += Ps[i][tid];
        partm[blockIdx.x * 64 + tid] = Qm[tid];
        parts[blockIdx.x * 64 + tid] = s;
    }
}

// ---------------------------------------------------------------- final softmax reduction (1024 partials)
__launch_bounds__(512)
__global__ void k_red2(const float* partm, const float* parts, float* mx, float* rden) {
    __shared__ float Lm[8][64], Ls[8][64];
    int q = threadIdx.x & 63, sub = threadIdx.x >> 6;
    float m = -3.0e38f, s = 0.f;
    for (int b = sub; b < 1024; b += 8) {
        float m2 = partm[b * 64 + q], s2 = parts[b * 64 + q];
        float mn = fmaxf(m, m2);
        s = s * __expf(m - mn) + s2 * __expf(m2 - mn);
        m = mn;
    }
    Lm[sub][q] = m; Ls[sub][q] = s;
    __syncthreads();
    if (sub == 0) {
#pragma unroll
        for (int i = 1; i < 8; ++i) {
            float m2 = Lm[i][q], s2 = Ls[i][q];
            float mn = fmaxf(m, m2);
            s = s * __expf(m - mn) + s2 * __expf(m2 - mn);
            m = mn;
        }
        mx[q] = m;
        rden[q] = 1.f / s;
    }
}

// ---------------------------------------------------------------- ctx + sim (R5 staged version)
__launch_bounds__(256)
__global__ void k_ctx(const float* att, const float* mx, const float* rden,
                      const u16* qp, const u16* ap, u16* sim) {
    __shared__ u16 P[64 * 64];
    __shared__ u16 QT[256 * 64];
    __shared__ u16 Y[64 * 264];
    __shared__ float MX[64], RD[64];
    int tid = threadIdx.x;
    long t0 = (long)blockIdx.x * 64;
    if (tid < 64) { MX[tid] = mx[tid]; RD[tid] = rden[tid]; }
    {
        int m = tid;
        char* row = (char*)QT + m * 128;
        u32 swz = (u32)((m & 7) << 4);
        for (int q = 0; q < 64; ++q)
            *(u16*)(row + ((u32)(q * 2) ^ swz)) = qp[q * 256 + m];
    }
    __syncthreads();
    {
        int t = tid >> 2, qq = tid & 3;
        const float* arow = att + (t0 + t) * 64 + qq * 16;
        char* prow = (char*)P + t * 128;
        u32 swz = (u32)((t & 7) << 4);
#pragma unroll
        for (int i4 = 0; i4 < 4; ++i4) {
            float4 fv = *(const float4*)(arow + i4 * 4);
            int q0 = qq * 16 + i4 * 4;
            float p0 = __expf(fv.x - MX[q0 + 0]) * RD[q0 + 0];
            float p1 = __expf(fv.y - MX[q0 + 1]) * RD[q0 + 1];
            float p2 = __expf(fv.z - MX[q0 + 2]) * RD[q0 + 2];
            float p3 = __expf(fv.w - MX[q0 + 3]) * RD[q0 + 3];
            *(u16*)(prow + ((u32)((q0 + 0) * 2) ^ swz)) = f2bf(p0);
            *(u16*)(prow + ((u32)((q0 + 1) * 2) ^ swz)) = f2bf(p1);
            *(u16*)(prow + ((u32)((q0 + 2) * 2) ^ swz)) = f2bf(p2);
            *(u16*)(prow + ((u32)((q0 + 3) * 2) ^ swz)) = f2bf(p3);
        }
    }
    __syncthreads();
    int wv = tid >> 6, lane = tid & 63, l15 = lane & 15, lq = lane >> 4;
    f32x4 acc[16] = {};
#pragma unroll
    for (int s = 0; s < 2; ++s) {
        int arow = wv * 16 + l15;
        s16x8 a = *(const s16x8*)((const char*)P + arow * 128 +
                                  ((u32)(s * 64 + lq * 16) ^ ((u32)(arow & 7) << 4)));
#pragma unroll
        for (int nt = 0; nt < 16; ++nt) {
            int br = nt * 16 + l15;
            s16x8 b = *(const s16x8*)((const char*)QT + br * 128 +
                                      ((u32)(s * 64 + lq * 16) ^ ((u32)(br & 7) << 4)));
            acc[nt] = mfma16(a, b, acc[nt]);
        }
    }
#pragma unroll
    for (int nt = 0; nt < 16; ++nt) {
        int m = nt * 16 + l15;
        int t = wv * 16 + lq * 4;
#pragma unroll
        for (int r = 0; r < 4; ++r) Y[(t + r) * 264 + m] = f2bf(acc[nt][r]);
    }
    __syncthreads();
    for (int j = tid; j < 2048; j += 256) {
        int t = j >> 5, c8 = (j & 31) * 8;
        s16x8 y = *(const s16x8*)(Y + t * 264 + c8);
        s16x8 a8 = *(const s16x8*)(ap + (t0 + t) * 256 + c8);
        s16x8 o;
#pragma unroll
        for (int e = 0; e < 8; ++e)
            o[e] = (short)f2bf(bf2f((u16)a8[e]) * bf2f((u16)y[e]));
        *(s16x8*)(sim + (t0 + t) * 256 + c8) = o;
    }
}

// ---------------------------------------------------------------- conv + dynamic max pool
// R5 geometry + T4 counted-vmcnt: per kb, STAGE(t+1) stays in flight across the
// compute (vmcnt(8) waits only tile t's loads); raw barriers, no full drain.
__launch_bounds__(512)
__global__ void k_conv(const u16* sim, const u16* WcT,
                       const int* starts, const int* sizes,
                       const float* bc1, const float* bc2, const float* bc3,
                       const float* bc4, const float* bc5,
                       u16* pools, int Ttot) {
    __shared__ u16 LB[2][32768];   // per buf: A bytes [0,32768), B bytes [32768,65536)
    int tid = threadIdx.x;
    int wv = tid >> 6, lane = tid & 63, l15 = lane & 15, lq = lane >> 4;
    int wm = wv >> 2, wn = wv & 3;
    int b = blockIdx.x;
    long s0 = starts[4 * b];
    int row8 = lane >> 3, seg = lane & 7;
    u32 sA = ((u32)(seg * 16)) ^ (((u32)(row8 & 7)) << 4);

    auto STAGE = [&](int nb, int w_, int dw_, int ic_) {
        int Krow = 256 * w_;
        long wbase = 65536L * ((w_ * (w_ - 1)) / 2);
#pragma unroll
        for (int it = 0; it < 4; ++it) {
            int c = wv * 4 + it;
            long g = s0 + dw_ + c * 8 + row8;
            if (g >= Ttot) g = Ttot - 1;
            const char* srcA = (const char*)sim + g * 512 + ic_ * 128 + sA;
            GLOAD(srcA, (char*)LB[nb] + c * 1024);
        }
#pragma unroll
        for (int it = 0; it < 4; ++it) {
            int c = wv * 4 + it;
            int o = c * 8 + row8;
            const char* srcB = (const char*)WcT +
                2L * (wbase + (long)o * Krow + dw_ * 256 + ic_ * 64) + sA;
            GLOAD(srcB, (char*)LB[nb] + 32768 + c * 1024);
        }
    };
    auto ADV = [](int& w_, int& dw_, int& ic_) {
        if (++ic_ == 4) { ic_ = 0; if (++dw_ == w_) { dw_ = 0; ++w_; } }
    };

    int wS = 1, dwS = 0, icS = 0;
    STAGE(0, wS, dwS, icS);
    ADV(wS, dwS, icS);
    asm volatile("s_waitcnt vmcnt(0)" ::: "memory");
    __builtin_amdgcn_s_barrier();

    int buf = 0;
    f32x4 acc[8][4] = {};
    int wC = 1, dwC = 0, icC = 0;
    for (int t = 0; t < 60; ++t) {
        if (t < 59) {
            STAGE(buf ^ 1, wS, dwS, icS);
            ADV(wS, dwS, icS);
            asm volatile("s_waitcnt vmcnt(8)" ::: "memory");   // tile t landed; t+1 in flight
        } else {
            asm volatile("s_waitcnt vmcnt(0)" ::: "memory");   // last tile landed
        }
        __builtin_amdgcn_s_barrier();                          // all waves landed tile t
        const char* Ab = (const char*)LB[buf];
        const char* Bb = (const char*)LB[buf] + 32768;
#pragma unroll
        for (int ks = 0; ks < 2; ++ks) {
            s16x8 A8[8], B4[4];
#pragma unroll
            for (int mt = 0; mt < 8; ++mt) {
                int row = wm * 128 + mt * 16 + l15;
                A8[mt] = *(const s16x8*)(Ab + row * 128 +
                          (((u32)(ks * 64 + lq * 16)) ^ (((u32)(row & 7)) << 4)));
            }
#pragma unroll
            for (int nt = 0; nt < 4; ++nt) {
                int o = wn * 64 + nt * 16 + l15;
                B4[nt] = *(const s16x8*)(Bb + o * 128 +
                          (((u32)(ks * 64 + lq * 16)) ^ (((u32)(o & 7)) << 4)));
            }
            __builtin_amdgcn_s_setprio(1);
#pragma unroll
            for (int mt = 0; mt < 8; ++mt)
#pragma unroll
                for (int nt = 0; nt < 4; ++nt)
                    acc[mt][nt] = mfma16(A8[mt], B4[nt], acc[mt][nt]);
            __builtin_amdgcn_s_setprio(0);
        }
        if (++icC == 4) {
            icC = 0;
            if (++dwC == wC) {
                dwC = 0;
                const float* bc = (wC == 1) ? bc1 : (wC == 2) ? bc2 : (wC == 3) ? bc3
                                  : (wC == 4) ? bc4 : bc5;
#pragma unroll
                for (int a2 = 0; a2 < 2; ++a2) {
                    int kans = b * 4 + wm * 2 + a2;
                    int valid = sizes[kans] - wC + 1;
#pragma unroll
                    for (int nt = 0; nt < 4; ++nt) {
                        float m = -3.0e38f;
#pragma unroll
                        for (int mth = 0; mth < 4; ++mth) {
                            int mt = a2 * 4 + mth;
#pragma unroll
                            for (int r = 0; r < 4; ++r) {
                                int pp = mth * 16 + lq * 4 + r;
                                float v = (pp < valid) ? acc[mt][nt][r] : -3.0e38f;
                                m = fmaxf(m, v);
                            }
                        }
                        m = fmaxf(m, __shfl_xor(m, 16, 64));
                        m = fmaxf(m, __shfl_xor(m, 32, 64));
                        if (lq == 0) {
                            int o = wn * 64 + nt * 16 + l15;
                            float pool = fmaxf(m + bc[o], 0.f);
                            pools[(long)kans * 1280 + (wC - 1) * 256 + o] = f2bf(pool);
                        }
                    }
                }
#pragma unroll
                for (int mt = 0; mt < 8; ++mt)
#pragma unroll
                    for (int nt = 0; nt < 4; ++nt)
                        acc[mt][nt] = f32x4{0.f, 0.f, 0.f, 0.f};
                ++wC;
            }
        }
        __builtin_amdgcn_s_barrier();   // all waves done reading buf before next STAGE overwrites
        buf ^= 1;
    }
}

// ---------------------------------------------------------------- head
__launch_bounds__(256)
__global__ void k_head(const u16* pools, const u16* WlT,
                       const float* bl, const float* Ws, const float* bs,
                       float* logits) {
    int tid = threadIdx.x;
    int k0 = blockIdx.x * 64;
    int wv = tid >> 6, lane = tid & 63, l15 = lane & 15, lq = lane >> 4;
    f32x4 acc[4][4] = {};
    for (int s = 0; s < 40; ++s) {
        s16x8 a[4], b[4];
#pragma unroll
        for (int mt = 0; mt < 4; ++mt) {
            int m = (wv * 4 + mt) * 16 + l15;
            a[mt] = *(const s16x8*)(WlT + (long)m * 1280 + s * 32 + lq * 8);
        }
#pragma unroll
        for (int nt = 0; nt < 4; ++nt) {
            int kk = k0 + nt * 16 + l15;
            b[nt] = *(const s16x8*)(pools + (long)kk * 1280 + s * 32 + lq * 8);
        }
#pragma unroll
        for (int mt = 0; mt < 4; ++mt)
#pragma unroll
            for (int nt = 0; nt < 4; ++nt)
                acc[mt][nt] = mfma16(a[mt], b[nt], acc[mt][nt]);
    }
    __shared__ float PS[4][4][16];
#pragma unroll
    for (int nt = 0; nt < 4; ++nt) {
        float p = 0.f;
#pragma unroll
        for (int mt = 0; mt < 4; ++mt) {
            int m0 = (wv * 4 + mt) * 16 + lq * 4;
#pragma unroll
            for (int r = 0; r < 4; ++r) {
                float h = tanhf(acc[mt][nt][r] + bl[m0 + r]);
                p += h * Ws[m0 + r];
            }
        }
        p += __shfl_xor(p, 16, 64);
        p += __shfl_xor(p, 32, 64);
        if (lq == 0) PS[wv][nt][l15] = p;
    }
    __syncthreads();
    if (tid < 64) {
        int nt = tid >> 4, i = tid & 15;
        float v = PS[0][nt][i] + PS[1][nt][i] + PS[2][nt][i] + PS[3][nt][i] + bs[0];
        logits[k0 + nt * 16 + i] = v;
    }
}

// ---------------------------------------------------------------- log_softmax over 1024
__global__ void k_lsm(const float* logits, float* out) {
    __shared__ float r1[16], r2[16];
    int tid = threadIdx.x;
    float v = logits[tid];
    float m = v;
#pragma unroll
    for (int off = 32; off >= 1; off >>= 1) m = fmaxf(m, __shfl_xor(m, off, 64));
    if ((tid & 63) == 0) r1[tid >> 6] = m;
    __syncthreads();
    if (tid < 16) {
        float t = r1[tid];
#pragma unroll
        for (int off = 8; off >= 1; off >>= 1) t = fmaxf(t, __shfl_xor(t, off, 64));
        r1[tid] = t;
    }
    __syncthreads();
    m = r1[0];
    float e = __expf(v - m);
    float s = e;
#pragma unroll
    for (int off = 32; off >= 1; off >>= 1) s += __shfl_xor(s, off, 64);
    if ((tid & 63) == 0) r2[tid >> 6] = s;
    __syncthreads();
    if (tid < 16) {
        float t = r2[tid];
#pragma unroll
        for (int off = 8; off >= 1; off >>= 1) t += __shfl_xor(t, off, 64);
        r2[tid] = t;
    }
    __syncthreads();
    out[tid] = v - m - logf(r2[0]);
}

// ---------------------------------------------------------------- launch
extern "C" void kernel_launch(void* const* d_in, const int* in_sizes, int n_in,
                              void* d_out, int out_size, void* d_ws, size_t ws_size,
                              hipStream_t stream) {
    const int*   data_q  = (const int*)d_in[0];
    const int*   data_as = (const int*)d_in[1];
    const int*   sizes   = (const int*)d_in[2];
    const float* emb = (const float*)d_in[3];
    const float* W1  = (const float*)d_in[4];
    const float* b1  = (const float*)d_in[5];
    const float* W2  = (const float*)d_in[6];
    const float* b2  = (const float*)d_in[7];
    const float* Wl  = (const float*)d_in[8];
    const float* bl  = (const float*)d_in[9];
    const float* Ws  = (const float*)d_in[10];
    const float* bs  = (const float*)d_in[11];
    const float* Wc1 = (const float*)d_in[12]; const float* bc1 = (const float*)d_in[13];
    const float* Wc2 = (const float*)d_in[14]; const float* bc2 = (const float*)d_in[15];
    const float* Wc3 = (const float*)d_in[16]; const float* bc3 = (const float*)d_in[17];
    const float* Wc4 = (const float*)d_in[18]; const float* bc4 = (const float*)d_in[19];
    const float* Wc5 = (const float*)d_in[20]; const float* bc5 = (const float*)d_in[21];
    int Ttot = in_sizes[1];

    char* ws = (char*)d_ws;
    u16*   WpT    = (u16*)  (ws + 0);
    u16*   WlT    = (u16*)  (ws + 327680);
    u16*   WcT    = (u16*)  (ws + 983040);
    u16*   qp     = (u16*)  (ws + 2949120);
    u16*   ap     = (u16*)  (ws + 2981888);
    float* att    = (float*)(ws + 36536320);
    float* mx     = (float*)(ws + 53379072);
    float* rden   = (float*)(ws + 53379328);
    u16*   sim    = (u16*)  (ws + 53379584);
    u16*   pools  = (u16*)  (ws + 86934016);
    float* logits = (float*)(ws + 89555456);
    int*   starts = (int*)  (ws + 89559552);
    u16*   xg     = (u16*)  (ws + 36536320);   // aliases att/sim region (dead interval)
    float* partm  = (float*)pools;
    float* parts  = (float*)((char*)pools + 262144);

    int Rtot = Ttot + 64;
    int gblocks = (Rtot * 80 + 511) / 512;

    k_prep<<<5761, 256, 0, stream>>>(W1, W2, Wl, Wc1, Wc2, Wc3, Wc4, Wc5,
                                     WpT, WlT, WcT, sizes, starts);
    k_gather<<<gblocks, 512, 0, stream>>>(data_as, data_q, emb, xg, Ttot);
    k_pgemm<<<1025, 512, 0, stream>>>(xg, WpT, b1, b2, ap, qp, Ttot);
    k_att<<<1024, 256, 0, stream>>>(qp, ap, att, partm, parts);
    k_red2<<<1, 512, 0, stream>>>(partm, parts, mx, rden);
    k_ctx<<<1024, 256, 0, stream>>>(att, mx, rden, qp, ap, sim);
    k_conv<<<256, 512, 0, stream>>>(sim, WcT, starts, sizes, bc1, bc2, bc3, bc4, bc5,
                                    pools, Ttot);
    k_head<<<16, 256, 0, stream>>>(pools, WlT, bl, Ws, bs, logits);
    k_lsm<<<1, 1024, 0, stream>>>(logits, (float*)d_out);
}

// Round 16
// 331.617 us; speedup vs baseline: 1.0405x; 1.0405x over previous
//
#include <hip/hip_runtime.h>

typedef unsigned short u16;
typedef unsigned int u32;
using s16x8 = __attribute__((ext_vector_type(8))) short;
using f32x4 = __attribute__((ext_vector_type(4))) float;
using u16x4 = __attribute__((ext_vector_type(4))) u16;

#define DEV __device__ __forceinline__

DEV u16 f2bf(float f) {
    u32 u = __builtin_bit_cast(u32, f);
    u32 r = (u + 0x7FFFu + ((u >> 16) & 1u)) >> 16;
    return (u16)r;
}
DEV float bf2f(u16 h) { return __builtin_bit_cast(float, ((u32)h) << 16); }

DEV f32x4 mfma16(s16x8 a, s16x8 b, f32x4 c) {
    return __builtin_amdgcn_mfma_f32_16x16x32_bf16(a, b, c, 0, 0, 0);
}

#define GLOAD(g, l) __builtin_amdgcn_global_load_lds( \
    (const __attribute__((address_space(1))) unsigned int*)(g), \
    (__attribute__((address_space(3))) unsigned int*)(l), 16, 0, 0)

// ---------------------------------------------------------------- fused prep + starts scan + gather
// blocks [0,2880): weight transposes (512 thr, 1,474,560 elems exactly)
// block 2880:      starts scan (first 256 thr)
// blocks (2880, +gblocks]: emb gather -> xg
__launch_bounds__(512)
__global__ void k_pre(const float* W1, const float* W2, const float* Wl,
                      const float* Wc1, const float* Wc2, const float* Wc3,
                      const float* Wc4, const float* Wc5,
                      u16* WpT, u16* WlT, u16* WcT,
                      const int* sizes, int* starts,
                      const int* data_as, const int* data_q, const float* emb,
                      u16* xg, int Ttot) {
    int tid = threadIdx.x;
    int b = blockIdx.x;
    if (b < 2880) {
        int idx = b * 512 + tid;
        if (idx < 512 * 320) {
            int n = idx / 320, k = idx - n * 320;
            float v = 0.f;
            if (k < 300) v = (n < 256) ? W1[k * 256 + n] : W2[k * 256 + (n - 256)];
            WpT[idx] = f2bf(v);
        } else if (idx < 512 * 320 + 256 * 1280) {
            int j2 = idx - 512 * 320;
            int m = j2 / 1280, j = j2 - m * 1280;
            WlT[j2] = f2bf(Wl[j * 256 + m]);
        } else {
            int j3 = idx - (512 * 320 + 256 * 1280);
            int wsz; int off;
            if (j3 < 65536)       { wsz = 1; off = 0; }
            else if (j3 < 196608) { wsz = 2; off = 65536; }
            else if (j3 < 393216) { wsz = 3; off = 196608; }
            else if (j3 < 655360) { wsz = 4; off = 393216; }
            else                  { wsz = 5; off = 655360; }
            int loc = j3 - off;
            int o = loc / (256 * wsz);
            int kk = loc - o * (256 * wsz);
            int dw = kk >> 8, i = kk & 255;
            const float* W = (wsz == 1) ? Wc1 : (wsz == 2) ? Wc2 : (wsz == 3) ? Wc3
                             : (wsz == 4) ? Wc4 : Wc5;
            WcT[j3] = f2bf(W[(o * 256 + i) * wsz + dw]);
        }
        return;
    }
    if (b == 2880) {
        if (tid >= 256) return;
        __shared__ int ps[256];
        int t4 = tid * 4;
        int v0 = sizes[t4], v1 = sizes[t4 + 1], v2 = sizes[t4 + 2], v3 = sizes[t4 + 3];
        int sum = v0 + v1 + v2 + v3;
        ps[tid] = sum;
        __syncthreads();
        for (int off = 1; off < 256; off <<= 1) {
            int add = (tid >= off) ? ps[tid - off] : 0;
            __syncthreads();
            ps[tid] += add;
            __syncthreads();
        }
        int base = tid ? ps[tid - 1] : 0;
        starts[t4] = base;
        starts[t4 + 1] = base + v0;
        starts[t4 + 2] = base + v0 + v1;
        starts[t4 + 3] = base + v0 + v1 + v2;
        return;
    }
    {
        int j = (b - 2881) * 512 + tid;
        int R = Ttot + 64;
        int row = j / 80;
        if (row >= R) return;
        int slot = j - row * 80;
        int tok = (row < Ttot) ? data_as[row] : data_q[row - Ttot];
        u16x4 h = {0, 0, 0, 0};
        if (slot < 75) {
            float4 f = *(const float4*)(emb + (long)tok * 300 + slot * 4);
            h[0] = f2bf(f.x); h[1] = f2bf(f.y); h[2] = f2bf(f.z); h[3] = f2bf(f.w);
        }
        *(u16x4*)(xg + (long)row * 320 + slot * 4) = h;
    }
}

// ---------------------------------------------------------------- projection GEMM (GLOAD-staged from xg)
__launch_bounds__(512)
__global__ void k_pgemm(const u16* xg, const u16* WpT, const float* b1, const float* b2,
                        u16* ap, u16* qp, int Ttot) {
    __shared__ u16 X[64 * 320];   // row pitch 640B, granule-XOR-swizzled storage
    int tid = threadIdx.x;
    bool isq = (blockIdx.x == 1024);
    u16* out = isq ? qp : ap;
    long row0 = isq ? 0 : (long)blockIdx.x * 64;
    long grow0 = isq ? Ttot : row0;           // row base in xg
    int wv = tid >> 6, lane = tid & 63, l15 = lane & 15, lq = lane >> 4;
    {
#pragma unroll
        for (int i = 0; i < 5; ++i) {
            int G = wv * 320 + i * 64 + lane;   // flat granule
            int rr = G / 40;                    // tile row 0..63
            int g = G - rr * 40;                // physical granule in row
            int gs = g ^ (rr & 7);              // source (logical) granule
            const char* src = (const char*)(xg + (grow0 + rr) * 320) + gs * 16;
            GLOAD(src, (char*)X + wv * 5120 + i * 1024);
        }
    }
    __syncthreads();
    f32x4 acc[4][4] = {};
    for (int s = 0; s < 10; ++s) {
        s16x8 a[4], b[4];
#pragma unroll
        for (int c = 0; c < 4; ++c) {
            int mt = 2 * wv + (c & 1) + (c >> 1) * 16;
            int o = mt * 16 + l15;
            a[c] = *(const s16x8*)(WpT + o * 320 + s * 32 + lq * 8);
        }
#pragma unroll
        for (int nt = 0; nt < 4; ++nt) {
            int r = nt * 16 + l15;
            b[nt] = *(const s16x8*)((const char*)X + r * 640 +
                                    ((u32)(s * 64 + lq * 16) ^ ((u32)(r & 7) << 4)));
        }
#pragma unroll
        for (int c = 0; c < 4; ++c)
#pragma unroll
            for (int nt = 0; nt < 4; ++nt)
                acc[c][nt] = mfma16(a[c], b[nt], acc[c][nt]);
    }
    __syncthreads();
    u16* Y = X; // reuse as [64][264] (pitch 264 u16 -> bank spread)
#pragma unroll
    for (int c = 0; c < 2; ++c) {
        int o0 = (2 * wv + c) * 16 + lq * 4;
#pragma unroll
        for (int nt = 0; nt < 4; ++nt) {
            int t = nt * 16 + l15;
            u16x4 h4;
#pragma unroll
            for (int r = 0; r < 4; ++r) {
                float xs = acc[c][nt][r] + b1[o0 + r];
                float xt = acc[c + 2][nt][r] + b2[o0 + r];
                float v = (1.f / (1.f + __expf(-xs))) * tanhf(xt);
                h4[r] = f2bf(v);
            }
            *(u16x4*)((char*)Y + t * 528 + o0 * 2) = h4;
        }
    }
    __syncthreads();
    for (int j = tid; j < 2048; j += 512) {
        int t = j >> 5, c8 = (j & 31) * 8;
        *(s16x8*)(out + (row0 + t) * 256 + c8) =
            *(const s16x8*)((const char*)Y + t * 528 + c8 * 2);
    }
}

// ---------------------------------------------------------------- att + lean in-register softmax stats
__launch_bounds__(256)
__global__ void k_att(const u16* qp, const u16* ap, float* att,
                      float* partm, float* parts) {
    __shared__ u16 Q[64 * 256];
    __shared__ u16 A[64 * 256];
    __shared__ float Pm[8][64], Ps[8][64], Qm[64];
    int tid = threadIdx.x;
    long t0 = (long)blockIdx.x * 64;
    for (int j = tid; j < 2048; j += 256) {
        int r = j >> 5, c8 = (j & 31) * 8;
        u32 dst = (u32)(c8 * 2) ^ ((u32)(r & 7) << 4);
        *(s16x8*)((char*)Q + r * 512 + dst) = *(const s16x8*)(qp + r * 256 + c8);
        *(s16x8*)((char*)A + r * 512 + dst) = *(const s16x8*)(ap + (t0 + r) * 256 + c8);
    }
    __syncthreads();
    int wv = tid >> 6, lane = tid & 63, l15 = lane & 15, lq = lane >> 4;
    f32x4 acc[4] = {};
    for (int s = 0; s < 8; ++s) {
        int brow = wv * 16 + l15;
        s16x8 b = *(const s16x8*)((const char*)A + brow * 512 +
                                  ((u32)(s * 64 + lq * 16) ^ ((u32)(brow & 7) << 4)));
#pragma unroll
        for (int mt = 0; mt < 4; ++mt) {
            int arow = mt * 16 + l15;
            s16x8 a = *(const s16x8*)((const char*)Q + arow * 512 +
                                      ((u32)(s * 64 + lq * 16) ^ ((u32)(arow & 7) << 4)));
            acc[mt] = mfma16(a, b, acc[mt]);
        }
    }
#pragma unroll
    for (int mt = 0; mt < 4; ++mt) {
        long t = t0 + wv * 16 + l15;
        *(f32x4*)(att + t * 64 + mt * 16 + lq * 4) = acc[mt];
    }
    float mxv[16];
#pragma unroll
    for (int mt = 0; mt < 4; ++mt)
#pragma unroll
        for (int r = 0; r < 4; ++r) mxv[mt * 4 + r] = acc[mt][r];
#pragma unroll
    for (int off = 1; off <= 8; off <<= 1)
#pragma unroll
        for (int i = 0; i < 16; ++i)
            mxv[i] = fmaxf(mxv[i], __shfl_xor(mxv[i], off, 64));
    if (l15 == 0) {
#pragma unroll
        for (int mt = 0; mt < 4; ++mt)
#pragma unroll
            for (int r = 0; r < 4; ++r)
                Pm[wv][mt * 16 + lq * 4 + r] = mxv[mt * 4 + r];
    }
    __syncthreads();
    if (tid < 64) {
        float g = Pm[0][tid];
#pragma unroll
        for (int i = 1; i < 8; ++i) g = fmaxf(g, Pm[i][tid]);
        Qm[tid] = g;
    }
    __syncthreads();
    float sv[16];
#pragma unroll
    for (int mt = 0; mt < 4; ++mt)
#pragma unroll
        for (int r = 0; r < 4; ++r) {
            int q = mt * 16 + lq * 4 + r;
            sv[mt * 4 + r] = __expf(acc[mt][r] - Qm[q]);
        }
#pragma unroll
    for (int off = 1; off <= 8; off <<= 1)
#pragma unroll
        for (int i = 0; i < 16; ++i)
            sv[i] += __shfl_xor(sv[i], off, 64);
    if (l15 == 0) {
#pragma unroll
        for (int mt = 0; mt < 4; ++mt)
#pragma unroll
            for (int r = 0; r < 4; ++r)
                Ps[wv][mt * 16 + lq * 4 + r] = sv[mt * 4 + r];
    }
    __syncthreads();
    if (tid < 64) {
        float s = Ps[0][tid];
#pragma unroll
        for (int i = 1; i < 8; ++i) s += Ps[i][tid];
        partm[blockIdx.x * 64 + tid] = Qm[tid];
        parts[blockIdx.x * 64 + tid] = s;
    }
}

// ---------------------------------------------------------------- final softmax reduction (1024 partials)
__launch_bounds__(512)
__global__ void k_red2(const float* partm, const float* parts, float* mx, float* rden) {
    __shared__ float Lm[8][64], Ls[8][64];
    int q = threadIdx.x & 63, sub = threadIdx.x >> 6;
    float m = -3.0e38f, s = 0.f;
    for (int b = sub; b < 1024; b += 8) {
        float m2 = partm[b * 64 + q], s2 = parts[b * 64 + q];
        float mn = fmaxf(m, m2);
        s = s * __expf(m - mn) + s2 * __expf(m2 - mn);
        m = mn;
    }
    Lm[sub][q] = m; Ls[sub][q] = s;
    __syncthreads();
    if (sub == 0) {
#pragma unroll
        for (int i = 1; i < 8; ++i) {
            float m2 = Lm[i][q], s2 = Ls[i][q];
            float mn = fmaxf(m, m2);
            s = s * __expf(m - mn) + s2 * __expf(m2 - mn);
            m = mn;
        }
        mx[q] = m;
        rden[q] = 1.f / s;
    }
}

// ---------------------------------------------------------------- ctx + sim (R5 staged version)
__launch_bounds__(256)
__global__ void k_ctx(const float* att, const float* mx, const float* rden,
                      const u16* qp, const u16* ap, u16* sim) {
    __shared__ u16 P[64 * 64];
    __shared__ u16 QT[256 * 64];
    __shared__ u16 Y[64 * 264];
    __shared__ float MX[64], RD[64];
    int tid = threadIdx.x;
    long t0 = (long)blockIdx.x * 64;
    if (tid < 64) { MX[tid] = mx[tid]; RD[tid] = rden[tid]; }
    {
        int m = tid;
        char* row = (char*)QT + m * 128;
        u32 swz = (u32)((m & 7) << 4);
        for (int q = 0; q < 64; ++q)
            *(u16*)(row + ((u32)(q * 2) ^ swz)) = qp[q * 256 + m];
    }
    __syncthreads();
    {
        int t = tid >> 2, qq = tid & 3;
        const float* arow = att + (t0 + t) * 64 + qq * 16;
        char* prow = (char*)P + t * 128;
        u32 swz = (u32)((t & 7) << 4);
#pragma unroll
        for (int i4 = 0; i4 < 4; ++i4) {
            float4 fv = *(const float4*)(arow + i4 * 4);
            int q0 = qq * 16 + i4 * 4;
            float p0 = __expf(fv.x - MX[q0 + 0]) * RD[q0 + 0];
            float p1 = __expf(fv.y - MX[q0 + 1]) * RD[q0 + 1];
            float p2 = __expf(fv.z - MX[q0 + 2]) * RD[q0 + 2];
            float p3 = __expf(fv.w - MX[q0 + 3]) * RD[q0 + 3];
            *(u16*)(prow + ((u32)((q0 + 0) * 2) ^ swz)) = f2bf(p0);
            *(u16*)(prow + ((u32)((q0 + 1) * 2) ^ swz)) = f2bf(p1);
            *(u16*)(prow + ((u32)((q0 + 2) * 2) ^ swz)) = f2bf(p2);
            *(u16*)(prow + ((u32)((q0 + 3) * 2) ^ swz)) = f2bf(p3);
        }
    }
    __syncthreads();
    int wv = tid >> 6, lane = tid & 63, l15 = lane & 15, lq = lane >> 4;
    f32x4 acc[16] = {};
#pragma unroll
    for (int s = 0; s < 2; ++s) {
        int arow = wv * 16 + l15;
        s16x8 a = *(const s16x8*)((const char*)P + arow * 128 +
                                  ((u32)(s * 64 + lq * 16) ^ ((u32)(arow & 7) << 4)));
#pragma unroll
        for (int nt = 0; nt < 16; ++nt) {
            int br = nt * 16 + l15;
            s16x8 b = *(const s16x8*)((const char*)QT + br * 128 +
                                      ((u32)(s * 64 + lq * 16) ^ ((u32)(br & 7) << 4)));
            acc[nt] = mfma16(a, b, acc[nt]);
        }
    }
#pragma unroll
    for (int nt = 0; nt < 16; ++nt) {
        int m = nt * 16 + l15;
        int t = wv * 16 + lq * 4;
#pragma unroll
        for (int r = 0; r < 4; ++r) Y[(t + r) * 264 + m] = f2bf(acc[nt][r]);
    }
    __syncthreads();
    for (int j = tid; j < 2048; j += 256) {
        int t = j >> 5, c8 = (j & 31) * 8;
        s16x8 y = *(const s16x8*)(Y + t * 264 + c8);
        s16x8 a8 = *(const s16x8*)(ap + (t0 + t) * 256 + c8);
        s16x8 o;
#pragma unroll
        for (int e = 0; e < 8; ++e)
            o[e] = (short)f2bf(bf2f((u16)a8[e]) * bf2f((u16)y[e]));
        *(s16x8*)(sim + (t0 + t) * 256 + c8) = o;
    }
}

// ---------------------------------------------------------------- conv + dynamic max pool (R5 geometry, exact revert)
__launch_bounds__(512)
__global__ void k_conv(const u16* sim, const u16* WcT,
                       const int* starts, const int* sizes,
                       const float* bc1, const float* bc2, const float* bc3,
                       const float* bc4, const float* bc5,
                       u16* pools, int Ttot) {
    __shared__ u16 LB[2][32768];   // per buf: A bytes [0,32768), B bytes [32768,65536)
    int tid = threadIdx.x;
    int wv = tid >> 6, lane = tid & 63, l15 = lane & 15, lq = lane >> 4;
    int wm = wv >> 2, wn = wv & 3;
    int b = blockIdx.x;
    long s0 = starts[4 * b];
    int row8 = lane >> 3, seg = lane & 7;
    u32 sA = ((u32)(seg * 16)) ^ (((u32)(row8 & 7)) << 4);

    auto STAGE = [&](int nb, int w_, int dw_, int ic_) {
        int Krow = 256 * w_;
        long wbase = 65536L * ((w_ * (w_ - 1)) / 2);
#pragma unroll
        for (int it = 0; it < 4; ++it) {
            int c = wv * 4 + it;
            long g = s0 + dw_ + c * 8 + row8;
            if (g >= Ttot) g = Ttot - 1;
            const char* srcA = (const char*)sim + g * 512 + ic_ * 128 + sA;
            GLOAD(srcA, (char*)LB[nb] + c * 1024);
        }
#pragma unroll
        for (int it = 0; it < 4; ++it) {
            int c = wv * 4 + it;
            int o = c * 8 + row8;
            const char* srcB = (const char*)WcT +
                2L * (wbase + (long)o * Krow + dw_ * 256 + ic_ * 64) + sA;
            GLOAD(srcB, (char*)LB[nb] + 32768 + c * 1024);
        }
    };
    auto ADV = [](int& w_, int& dw_, int& ic_) {
        if (++ic_ == 4) { ic_ = 0; if (++dw_ == w_) { dw_ = 0; ++w_; } }
    };

    int wS = 1, dwS = 0, icS = 0;
    STAGE(0, wS, dwS, icS);
    ADV(wS, dwS, icS);
    __syncthreads();

    int buf = 0;
    f32x4 acc[8][4] = {};
    int wC = 1, dwC = 0, icC = 0;
    for (int t = 0; t < 60; ++t) {
        if (t < 59) { STAGE(buf ^ 1, wS, dwS, icS); ADV(wS, dwS, icS); }
        const char* Ab = (const char*)LB[buf];
        const char* Bb = (const char*)LB[buf] + 32768;
#pragma unroll
        for (int ks = 0; ks < 2; ++ks) {
            s16x8 A8[8], B4[4];
#pragma unroll
            for (int mt = 0; mt < 8; ++mt) {
                int row = wm * 128 + mt * 16 + l15;
                A8[mt] = *(const s16x8*)(Ab + row * 128 +
                          (((u32)(ks * 64 + lq * 16)) ^ (((u32)(row & 7)) << 4)));
            }
#pragma unroll
            for (int nt = 0; nt < 4; ++nt) {
                int o = wn * 64 + nt * 16 + l15;
                B4[nt] = *(const s16x8*)(Bb + o * 128 +
                          (((u32)(ks * 64 + lq * 16)) ^ (((u32)(o & 7)) << 4)));
            }
            __builtin_amdgcn_s_setprio(1);
#pragma unroll
            for (int mt = 0; mt < 8; ++mt)
#pragma unroll
                for (int nt = 0; nt < 4; ++nt)
                    acc[mt][nt] = mfma16(A8[mt], B4[nt], acc[mt][nt]);
            __builtin_amdgcn_s_setprio(0);
        }
        if (++icC == 4) {
            icC = 0;
            if (++dwC == wC) {
                dwC = 0;
                const float* bc = (wC == 1) ? bc1 : (wC == 2) ? bc2 : (wC == 3) ? bc3
                                  : (wC == 4) ? bc4 : bc5;
#pragma unroll
                for (int a2 = 0; a2 < 2; ++a2) {
                    int kans = b * 4 + wm * 2 + a2;
                    int valid = sizes[kans] - wC + 1;
#pragma unroll
                    for (int nt = 0; nt < 4; ++nt) {
                        float m = -3.0e38f;
#pragma unroll
                        for (int mth = 0; mth < 4; ++mth) {
                            int mt = a2 * 4 + mth;
#pragma unroll
                            for (int r = 0; r < 4; ++r) {
                                int pp = mth * 16 + lq * 4 + r;
                                float v = (pp < valid) ? acc[mt][nt][r] : -3.0e38f;
                                m = fmaxf(m, v);
                            }
                        }
                        m = fmaxf(m, __shfl_xor(m, 16, 64));
                        m = fmaxf(m, __shfl_xor(m, 32, 64));
                        if (lq == 0) {
                            int o = wn * 64 + nt * 16 + l15;
                            float pool = fmaxf(m + bc[o], 0.f);
                            pools[(long)kans * 1280 + (wC - 1) * 256 + o] = f2bf(pool);
                        }
                    }
                }
#pragma unroll
                for (int mt = 0; mt < 8; ++mt)
#pragma unroll
                    for (int nt = 0; nt < 4; ++nt)
                        acc[mt][nt] = f32x4{0.f, 0.f, 0.f, 0.f};
                ++wC;
            }
        }
        __syncthreads();
        buf ^= 1;
    }
}

// ---------------------------------------------------------------- head
__launch_bounds__(256)
__global__ void k_head(const u16* pools, const u16* WlT,
                       const float* bl, const float* Ws, const float* bs,
                       float* logits) {
    int tid = threadIdx.x;
    int k0 = blockIdx.x * 64;
    int wv = tid >> 6, lane = tid & 63, l15 = lane & 15, lq = lane >> 4;
    f32x4 acc[4][4] = {};
    for (int s = 0; s < 40; ++s) {
        s16x8 a[4], b[4];
#pragma unroll
        for (int mt = 0; mt < 4; ++mt) {
            int m = (wv * 4 + mt) * 16 + l15;
            a[mt] = *(const s16x8*)(WlT + (long)m * 1280 + s * 32 + lq * 8);
        }
#pragma unroll
        for (int nt = 0; nt < 4; ++nt) {
            int kk = k0 + nt * 16 + l15;
            b[nt] = *(const s16x8*)(pools + (long)kk * 1280 + s * 32 + lq * 8);
        }
#pragma unroll
        for (int mt = 0; mt < 4; ++mt)
#pragma unroll
            for (int nt = 0; nt < 4; ++nt)
                acc[mt][nt] = mfma16(a[mt], b[nt], acc[mt][nt]);
    }
    __shared__ float PS[4][4][16];
#pragma unroll
    for (int nt = 0; nt < 4; ++nt) {
        float p = 0.f;
#pragma unroll
        for (int mt = 0; mt < 4; ++mt) {
            int m0 = (wv * 4 + mt) * 16 + lq * 4;
#pragma unroll
            for (int r = 0; r < 4; ++r) {
                float h = tanhf(acc[mt][nt][r] + bl[m0 + r]);
                p += h * Ws[m0 + r];
            }
        }
        p += __shfl_xor(p, 16, 64);
        p += __shfl_xor(p, 32, 64);
        if (lq == 0) PS[wv][nt][l15] = p;
    }
    __syncthreads();
    if (tid < 64) {
        int nt = tid >> 4, i = tid & 15;
        float v = PS[0][nt][i] + PS[1][nt][i] + PS[2][nt][i] + PS[3][nt][i] + bs[0];
        logits[k0 + nt * 16 + i] = v;
    }
}

// ---------------------------------------------------------------- log_softmax over 1024
__global__ void k_lsm(const float* logits, float* out) {
    __shared__ float r1[16], r2[16];
    int tid = threadIdx.x;
    float v = logits[tid];
    float m = v;
#pragma unroll
    for (int off = 32; off >= 1; off >>= 1) m = fmaxf(m, __shfl_xor(m, off, 64));
    if ((tid & 63) == 0) r1[tid >> 6] = m;
    __syncthreads();
    if (tid < 16) {
        float t = r1[tid];
#pragma unroll
        for (int off = 8; off >= 1; off >>= 1) t = fmaxf(t, __shfl_xor(t, off, 64));
        r1[tid] = t;
    }
    __syncthreads();
    m = r1[0];
    float e = __expf(v - m);
    float s = e;
#pragma unroll
    for (int off = 32; off >= 1; off >>= 1) s += __shfl_xor(s, off, 64);
    if ((tid & 63) == 0) r2[tid >> 6] = s;
    __syncthreads();
    if (tid < 16) {
        float t = r2[tid];
#pragma unroll
        for (int off = 8; off >= 1; off >>= 1) t += __shfl_xor(t, off, 64);
        r2[tid] = t;
    }
    __syncthreads();
    out[tid] = v - m - logf(r2[0]);
}

// ---------------------------------------------------------------- launch
extern "C" void kernel_launch(void* const* d_in, const int* in_sizes, int n_in,
                              void* d_out, int out_size, void* d_ws, size_t ws_size,
                              hipStream_t stream) {
    const int*   data_q  = (const int*)d_in[0];
    const int*   data_as = (const int*)d_in[1];
    const int*   sizes   = (const int*)d_in[2];
    const float* emb = (const float*)d_in[3];
    const float* W1  = (const float*)d_in[4];
    const float* b1  = (const float*)d_in[5];
    const float* W2  = (const float*)d_in[6];
    const float* b2  = (const float*)d_in[7];
    const float* Wl  = (const float*)d_in[8];
    const float* bl  = (const float*)d_in[9];
    const float* Ws  = (const float*)d_in[10];
    const float* bs  = (const float*)d_in[11];
    const float* Wc1 = (const float*)d_in[12]; const float* bc1 = (const float*)d_in[13];
    const float* Wc2 = (const float*)d_in[14]; const float* bc2 = (const float*)d_in[15];
    const float* Wc3 = (const float*)d_in[16]; const float* bc3 = (const float*)d_in[17];
    const float* Wc4 = (const float*)d_in[18]; const float* bc4 = (const float*)d_in[19];
    const float* Wc5 = (const float*)d_in[20]; const float* bc5 = (const float*)d_in[21];
    int Ttot = in_sizes[1];

    char* ws = (char*)d_ws;
    u16*   WpT    = (u16*)  (ws + 0);
    u16*   WlT    = (u16*)  (ws + 327680);
    u16*   WcT    = (u16*)  (ws + 983040);
    u16*   qp     = (u16*)  (ws + 2949120);
    u16*   ap     = (u16*)  (ws + 2981888);
    float* att    = (float*)(ws + 36536320);
    float* mx     = (float*)(ws + 53379072);
    float* rden   = (float*)(ws + 53379328);
    u16*   sim    = (u16*)  (ws + 53379584);
    u16*   pools  = (u16*)  (ws + 86934016);
    float* logits = (float*)(ws + 89555456);
    int*   starts = (int*)  (ws + 89559552);
    u16*   xg     = (u16*)  (ws + 36536320);   // aliases att/sim region (dead interval)
    float* partm  = (float*)pools;
    float* parts  = (float*)((char*)pools + 262144);

    int Rtot = Ttot + 64;
    int gblocks = (Rtot * 80 + 511) / 512;

    k_pre<<<2881 + gblocks, 512, 0, stream>>>(W1, W2, Wl, Wc1, Wc2, Wc3, Wc4, Wc5,
                                              WpT, WlT, WcT, sizes, starts,
                                              data_as, data_q, emb, xg, Ttot);
    k_pgemm<<<1025, 512, 0, stream>>>(xg, WpT, b1, b2, ap, qp, Ttot);
    k_att<<<1024, 256, 0, stream>>>(qp, ap, att, partm, parts);
    k_red2<<<1, 512, 0, stream>>>(partm, parts, mx, rden);
    k_ctx<<<1024, 256, 0, stream>>>(att, mx, rden, qp, ap, sim);
    k_conv<<<256, 512, 0, stream>>>(sim, WcT, starts, sizes, bc1, bc2, bc3, bc4, bc5,
                                    pools, Ttot);
    k_head<<<16, 256, 0, stream>>>(pools, WlT, bl, Ws, bs, logits);
    k_lsm<<<1, 1024, 0, stream>>>(logits, (float*)d_out);
}